// Round 2
// baseline (1333.817 us; speedup 1.0000x reference)
//
#include <hip/hip_runtime.h>

#define NV 40962
#define NP 10242
#define KNB 7
#define C1 64
#define C2 64
#define C3 128
#define INC 8
#define OC 64
#define B 8
#define FCK (C3*NP)        // 1310976
#define NCHUNK (FCK/128)   // 10242
#define FBLK 1024

// ---------------- conv1: h1t[b][n][c] = relu(W1 @ x + b1) ----------------
__global__ __launch_bounds__(256) void k_conv1(const float* __restrict__ x,
        const float* __restrict__ W1, const float* __restrict__ b1,
        float* __restrict__ h1t) {
    __shared__ float sW[C1*INC];
    __shared__ float sb[C1];
    int tid = threadIdx.x;
    for (int i = tid; i < C1*INC; i += 256) sW[i] = W1[i];   // 512 floats, 256 threads
    if (tid < C1) sb[tid] = b1[tid];
    __syncthreads();
    long gid = (long)blockIdx.x*256 + tid;
    if (gid >= (long)B*NV) return;
    int b = (int)(gid / NV);
    int n = (int)(gid % NV);
    float xv[INC];
    const float* xb = x + (size_t)b*INC*NV + n;
#pragma unroll
    for (int c = 0; c < INC; ++c) xv[c] = xb[(size_t)c*NV];
    float4* outp = (float4*)(h1t + (size_t)gid*C1);
#pragma unroll
    for (int o4 = 0; o4 < C1/4; ++o4) {
        float4 r;
        float* rp = (float*)&r;
#pragma unroll
        for (int j = 0; j < 4; ++j) {
            int o = o4*4+j;
            float a = sb[o];
#pragma unroll
            for (int c = 0; c < INC; ++c) a += xv[c]*sW[o*INC+c];
            rp[j] = fmaxf(a, 0.f);
        }
        outp[o4] = r;
    }
}

// ---------------- conv2: h2t[b][n][o] = relu(sum_{c,k} h1t[b][neb(n,k)][c]*W2[o][c][k] + b2[o])
// block: one b, 64-vertex tile; per k: stage X[c][v] and W2k[c][o] in LDS, 4x4 reg tile.
__global__ __launch_bounds__(256) void k_conv2(const float* __restrict__ h1t,
        const int* __restrict__ nebs, const float* __restrict__ W2,
        const float* __restrict__ b2, float* __restrict__ h2t) {
    __shared__ float sX[C1][64];    // [c][v]
    __shared__ float sW[C1][C2];    // [c][o]
    __shared__ float sb[C2];
    int tid = threadIdx.x;
    int b = blockIdx.y;
    int vbase = blockIdx.x * 64;
    if (tid < C2) sb[tid] = b2[tid];
    int tv = tid & 15, to = tid >> 4;   // v = tv*4+i, o = to*4+j
    float acc[4][4] = {};
    int v = tid & 63;                   // staging vertex
    int cg = tid >> 6;                  // 0..3 -> c range cg*16..cg*16+15
    int vg = vbase + v;
    bool vok = vg < NV;
    for (int k = 0; k < KNB; ++k) {
        __syncthreads();
        int row = vok ? nebs[(size_t)vg*KNB + k] : 0;
        const float4* src = (const float4*)(h1t + ((size_t)b*NV + row)*C1 + cg*16);
#pragma unroll
        for (int q = 0; q < 4; ++q) {
            float4 d = src[q];
            int c0 = cg*16 + q*4;
            sX[c0+0][v] = d.x; sX[c0+1][v] = d.y; sX[c0+2][v] = d.z; sX[c0+3][v] = d.w;
        }
        {
            int o = tid & 63;
#pragma unroll
            for (int q = 0; q < 16; ++q) {
                int c = cg*16 + q;
                sW[c][o] = W2[(size_t)o*(C1*KNB) + c*KNB + k];
            }
        }
        __syncthreads();
#pragma unroll 8
        for (int c = 0; c < C1; ++c) {
            float4 xa = *(const float4*)&sX[c][tv*4];
            float4 wb = *(const float4*)&sW[c][to*4];
            const float* xs = (const float*)&xa;
            const float* wsp = (const float*)&wb;
#pragma unroll
            for (int i = 0; i < 4; ++i)
#pragma unroll
                for (int j = 0; j < 4; ++j)
                    acc[i][j] += xs[i]*wsp[j];
        }
    }
#pragma unroll
    for (int i = 0; i < 4; ++i) {
        int vg2 = vbase + tv*4 + i;
        if (vg2 < NV) {
            float4 r;
            float* rp = (float*)&r;
#pragma unroll
            for (int j = 0; j < 4; ++j) rp[j] = fmaxf(acc[i][j] + sb[to*4+j], 0.f);
            *(float4*)(h2t + ((size_t)b*NV + vg2)*C2 + to*4) = r;
        }
    }
}

// ---------------- pool: p[b][v][c] = max_k h2t[b][neb(v,k)][c] ----------------
__global__ __launch_bounds__(256) void k_pool(const float* __restrict__ h2t,
        const int* __restrict__ nebs, float* __restrict__ p) {
    long gid = (long)blockIdx.x*256 + threadIdx.x;
    if (gid >= (long)B*NP) return;
    int b = (int)(gid / NP);
    int v = (int)(gid % NP);
    float4 m[16];
#pragma unroll
    for (int j = 0; j < 16; ++j) m[j] = make_float4(-1e30f,-1e30f,-1e30f,-1e30f);
    for (int k = 0; k < KNB; ++k) {
        int row = nebs[(size_t)v*KNB + k];
        const float4* src = (const float4*)(h2t + ((size_t)b*NV + row)*C2);
#pragma unroll
        for (int j = 0; j < 16; ++j) {
            float4 d = src[j];
            m[j].x = fmaxf(m[j].x, d.x);
            m[j].y = fmaxf(m[j].y, d.y);
            m[j].z = fmaxf(m[j].z, d.z);
            m[j].w = fmaxf(m[j].w, d.w);
        }
    }
    float4* dst = (float4*)(p + (size_t)gid*C2);
#pragma unroll
    for (int j = 0; j < 16; ++j) dst[j] = m[j];
}

// ---------------- conv3: h3[b][o][v] = relu(W3 @ p + b3), W3 via uniform s_loads
__global__ __launch_bounds__(256) void k_conv3(const float* __restrict__ p,
        const float* __restrict__ W3, const float* __restrict__ b3,
        float* __restrict__ h3) {
    long gid = (long)blockIdx.x*256 + threadIdx.x;
    if (gid >= (long)B*NP) return;
    int b = (int)(gid / NP);
    int v = (int)(gid % NP);
    float4 pv[16];
    const float4* src = (const float4*)(p + (size_t)gid*C2);
#pragma unroll
    for (int j = 0; j < 16; ++j) pv[j] = src[j];
    float* dst = h3 + (size_t)b*C3*NP + v;
    const float4* W34 = (const float4*)W3;
#pragma unroll 1
    for (int og = 0; og < C3; og += 32) {
        float acc[32];
#pragma unroll
        for (int j = 0; j < 32; ++j) acc[j] = b3[og+j];
#pragma unroll
        for (int c4 = 0; c4 < 16; ++c4) {
            float4 x4 = pv[c4];
#pragma unroll
            for (int j = 0; j < 32; ++j) {
                float4 w4 = W34[(og+j)*16 + c4];
                acc[j] += x4.x*w4.x + x4.y*w4.y + x4.z*w4.z + x4.w*w4.w;
            }
        }
#pragma unroll
        for (int j = 0; j < 32; ++j) dst[(size_t)(og+j)*NP] = fmaxf(acc[j], 0.f);
    }
}

// ---------------- fc: split-K partials over chunks of 128 ----------------
__global__ __launch_bounds__(256) void k_fc(const float* __restrict__ h3,
        const float* __restrict__ Wfc, float* __restrict__ partial) {
    __shared__ float sH[B][128];
    __shared__ float sW[OC][129];   // pad -> conflict-free
    int tid = threadIdx.x;
    int o = tid & 63;
    int tb = tid >> 6;      // 0..3 -> b pair (2*tb, 2*tb+1)
    float acc0 = 0.f, acc1 = 0.f;
    for (int ch = blockIdx.x; ch < NCHUNK; ch += FBLK) {
        size_t i0 = (size_t)ch * 128;
        __syncthreads();
#pragma unroll
        for (int j = 0; j < 4; ++j) {
            int idx = tid + j*256;       // 0..1023
            int bb = idx >> 7, ii = idx & 127;
            sH[bb][ii] = h3[(size_t)bb*FCK + i0 + ii];
        }
#pragma unroll
        for (int j = 0; j < 32; ++j) {
            int idx = tid + j*256;       // 0..8191
            int oo = idx >> 7, ii = idx & 127;
            sW[oo][ii] = Wfc[(size_t)oo*FCK + i0 + ii];
        }
        __syncthreads();
#pragma unroll 8
        for (int ii = 0; ii < 128; ++ii) {
            float w = sW[o][ii];
            acc0 += w * sH[2*tb][ii];
            acc1 += w * sH[2*tb+1][ii];
        }
    }
    partial[((size_t)blockIdx.x*B + 2*tb  )*OC + o] = acc0;
    partial[((size_t)blockIdx.x*B + 2*tb+1)*OC + o] = acc1;
}

__global__ void k_fcred(const float* __restrict__ partial, const float* __restrict__ bfc,
        float* __restrict__ out) {
    int b = blockIdx.x;
    int o = threadIdx.x;
    float s = 0.f;
    for (int j = 0; j < FBLK; ++j) s += partial[((size_t)j*B + b)*OC + o];
    out[b*OC + o] = s + bfc[o];
}

extern "C" void kernel_launch(void* const* d_in, const int* in_sizes, int n_in,
                              void* d_out, int out_size, void* d_ws, size_t ws_size,
                              hipStream_t stream) {
    const float* x    = (const float*)d_in[0];
    const int*   nebs = (const int*)d_in[1];
    const float* W1   = (const float*)d_in[2];
    const float* b1   = (const float*)d_in[3];
    const float* W2   = (const float*)d_in[4];
    const float* b2   = (const float*)d_in[5];
    const float* W3   = (const float*)d_in[6];
    const float* b3   = (const float*)d_in[7];
    const float* Wfc  = (const float*)d_in[8];
    const float* bfc  = (const float*)d_in[9];
    float* out = (float*)d_out;

    char* ws = (char*)d_ws;
    float* h1t  = (float*)(ws);                 // 8*40962*64*4 = 83,890,176 B
    float* h2t  = (float*)(ws + 83890176);      // 83,890,176 B
    float* pbuf = (float*)(ws + 167780352);     // 8*10242*64*4 = 20,975,616 B
    float* h3   = (float*)(ws);                 // reuse h1t region (dead after conv2)
    float* part = (float*)(ws + 50331648);      // 1024*8*64*4 = 2,097,152 B (after h3's 41.95 MB)

    // conv1
    {
        long total = (long)B*NV;
        int blocks = (int)((total + 255) / 256);
        k_conv1<<<blocks, 256, 0, stream>>>(x, W1, b1, h1t);
    }
    // conv2
    {
        dim3 grid((NV + 63) / 64, B);
        k_conv2<<<grid, 256, 0, stream>>>(h1t, nebs, W2, b2, h2t);
    }
    // pool
    {
        long total = (long)B*NP;
        int blocks = (int)((total + 255) / 256);
        k_pool<<<blocks, 256, 0, stream>>>(h2t, nebs, pbuf);
    }
    // conv3
    {
        long total = (long)B*NP;
        int blocks = (int)((total + 255) / 256);
        k_conv3<<<blocks, 256, 0, stream>>>(pbuf, W3, b3, h3);
    }
    // fc
    k_fc<<<FBLK, 256, 0, stream>>>(h3, Wfc, part);
    k_fcred<<<B, OC, 0, stream>>>(part, bfc, out);
}

// Round 4
// 638.013 us; speedup vs baseline: 2.0906x; 2.0906x over previous
//
#include <hip/hip_runtime.h>

#define NV 40962
#define NP 10242
#define KNB 7
#define C1 64
#define C2 64
#define C3 128
#define INC 8
#define OC 64
#define B 8
#define FCK (C3*NP)        // 1310976
#define NCHUNK (FCK/128)   // 10242
#define FBLK 1024

typedef __attribute__((ext_vector_type(8))) __bf16 bf16x8;
typedef __attribute__((ext_vector_type(4))) float f32x4;
typedef unsigned short ushort_t;
typedef unsigned int uint_t;

static __device__ __forceinline__ ushort_t f2bf(float f) {
    uint_t u = __float_as_uint(f);
    u = (u + 0x7FFFu + ((u >> 16) & 1u)) >> 16;
    return (ushort_t)u;
}
static __device__ __forceinline__ uint_t pack2(float a, float b) {
    return (uint_t)f2bf(a) | ((uint_t)f2bf(b) << 16);
}

// ---------------- weight swizzle: W2 -> Wsw (fragment order), W3 -> W3sw ----------------
__global__ __launch_bounds__(256) void k_wswz(const float* __restrict__ W2,
        const float* __restrict__ W3, ushort_t* __restrict__ wsw) {
    int idx = blockIdx.x*256 + threadIdx.x;
    if (idx < 28672) {
        int j = idx & 7, lane = (idx >> 3) & 63, rest = idx >> 9; // rest = kstep*4+ntile
        int ntile = rest & 3, kstep = rest >> 2;
        int quad = lane >> 4, col = lane & 15;
        int k = kstep*32 + quad*8 + j;
        int o = ntile*16 + col;
        int c = k & 63, knb = k >> 6;
        wsw[idx] = f2bf(W2[(size_t)o*(C1*KNB) + c*KNB + knb]);
    } else if (idx < 28672 + 8192) {
        int s = idx - 28672;
        int j = s & 7, lane = (s >> 3) & 63, rest = s >> 9;      // rest = kstep*8+ntile
        int ntile = rest & 7, kstep = rest >> 3;
        int quad = lane >> 4, col = lane & 15;
        int c = kstep*32 + quad*8 + j;
        int o3 = ntile*16 + col;
        wsw[idx] = f2bf(W3[(size_t)o3*C2 + c]);
    }
}

// ---------------- conv1: h1bf[n][b][c] = bf16(relu(W1 @ x + b1)) ----------------
__global__ __launch_bounds__(256) void k_conv1(const float* __restrict__ x,
        const float* __restrict__ W1, const float* __restrict__ b1,
        ushort_t* __restrict__ h1bf) {
    __shared__ float sW[C1*INC];
    __shared__ float sb[C1];
    int tid = threadIdx.x;
    for (int i = tid; i < C1*INC; i += 256) sW[i] = W1[i];
    if (tid < C1) sb[tid] = b1[tid];
    __syncthreads();
    long g = (long)blockIdx.x*256 + tid;
    if (g >= (long)NV*B) return;
    int n = (int)(g >> 3);
    int b = (int)(g & 7);
    float xv[INC];
#pragma unroll
    for (int c = 0; c < INC; ++c) xv[c] = x[(size_t)b*INC*NV + (size_t)c*NV + n];
    uint4* outp = (uint4*)(h1bf + ((size_t)n*B + b)*C1);
#pragma unroll
    for (int og = 0; og < 8; ++og) {
        float h[8];
#pragma unroll
        for (int j = 0; j < 8; ++j) {
            int o = og*8 + j;
            float a = sb[o];
#pragma unroll
            for (int c = 0; c < INC; ++c) a += xv[c]*sW[o*INC + c];
            h[j] = fmaxf(a, 0.f);
        }
        uint4 u;
        u.x = pack2(h[0], h[1]); u.y = pack2(h[2], h[3]);
        u.z = pack2(h[4], h[5]); u.w = pack2(h[6], h[7]);
        outp[og] = u;
    }
}

// ---------------- conv2 MFMA: m = v*8+b (M=NV*8), K=448, N=64 ----------------
__global__ __launch_bounds__(256) void k_conv2m(const ushort_t* __restrict__ h1bf,
        const int* __restrict__ nebs, const ushort_t* __restrict__ wsw,
        const float* __restrict__ b2, ushort_t* __restrict__ h2bf) {
    int tid = threadIdx.x;
    int wave = tid >> 6, lane = tid & 63;
    int quad = lane >> 4, col = lane & 15;
    int bsub = col & 7;
    int mblock = blockIdx.x * 128;
    int mbase[2];
    int rowt[2][KNB];
    f32x4 acc[2][4];
#pragma unroll
    for (int t = 0; t < 2; ++t) {
        mbase[t] = mblock + wave*32 + t*16;
        int v = (mbase[t] + col) >> 3;
        int vc = v < NV ? v : 0;
#pragma unroll
        for (int kn = 0; kn < KNB; ++kn) rowt[t][kn] = nebs[(size_t)vc*KNB + kn];
#pragma unroll
        for (int nt = 0; nt < 4; ++nt) acc[t][nt] = (f32x4){0.f, 0.f, 0.f, 0.f};
    }
    float bv[4];
#pragma unroll
    for (int nt = 0; nt < 4; ++nt) bv[nt] = b2[nt*16 + col];
    const bf16x8* W = (const bf16x8*)wsw;
#pragma unroll
    for (int ks = 0; ks < 14; ++ks) {
        int knb = ks >> 1;
        int c0 = (ks & 1)*32 + quad*8;
        bf16x8 a0 = *(const bf16x8*)(h1bf + ((size_t)rowt[0][knb]*B + bsub)*C1 + c0);
        bf16x8 a1 = *(const bf16x8*)(h1bf + ((size_t)rowt[1][knb]*B + bsub)*C1 + c0);
#pragma unroll
        for (int nt = 0; nt < 4; ++nt) {
            bf16x8 bf = W[(ks*4 + nt)*64 + lane];
            acc[0][nt] = __builtin_amdgcn_mfma_f32_16x16x32_bf16(a0, bf, acc[0][nt], 0, 0, 0);
            acc[1][nt] = __builtin_amdgcn_mfma_f32_16x16x32_bf16(a1, bf, acc[1][nt], 0, 0, 0);
        }
    }
#pragma unroll
    for (int t = 0; t < 2; ++t) {
#pragma unroll
        for (int r = 0; r < 4; ++r) {
            int m = mbase[t] + quad*4 + r;
            if ((m >> 3) < NV) {
#pragma unroll
                for (int nt = 0; nt < 4; ++nt) {
                    float val = fmaxf(acc[t][nt][r] + bv[nt], 0.f);
                    h2bf[(size_t)m*C2 + nt*16 + col] = f2bf(val);
                }
            }
        }
    }
}

// ---------------- pool: pbf[v][b][c] = max_k h2bf[neb][b][c] (bf16) ----------------
__global__ __launch_bounds__(256) void k_pool(const ushort_t* __restrict__ h2bf,
        const int* __restrict__ nebs, ushort_t* __restrict__ pbf) {
    long t = (long)blockIdx.x*256 + threadIdx.x;
    if (t >= (long)NP*32) return;
    int cg = (int)(t & 3);
    int b  = (int)((t >> 2) & 7);
    int v  = (int)(t >> 5);
    float m[16];
#pragma unroll
    for (int i = 0; i < 16; ++i) m[i] = -1e30f;
    for (int kn = 0; kn < KNB; ++kn) {
        int row = nebs[(size_t)v*KNB + kn];
        const uint4* src = (const uint4*)(h2bf + ((size_t)row*B + b)*C2 + cg*16);
        uint4 u0 = src[0], u1 = src[1];
        uint_t ws[8] = {u0.x, u0.y, u0.z, u0.w, u1.x, u1.y, u1.z, u1.w};
#pragma unroll
        for (int i = 0; i < 8; ++i) {
            float lo = __uint_as_float((ws[i] & 0xFFFFu) << 16);
            float hi = __uint_as_float(ws[i] & 0xFFFF0000u);
            m[2*i]   = fmaxf(m[2*i], lo);
            m[2*i+1] = fmaxf(m[2*i+1], hi);
        }
    }
    uint_t op[8];
#pragma unroll
    for (int i = 0; i < 8; ++i) {
        uint_t lo = __float_as_uint(m[2*i]) >> 16;            // exact (values are bf16)
        uint_t hi = __float_as_uint(m[2*i+1]) & 0xFFFF0000u;  // exact
        op[i] = lo | hi;
    }
    uint4* dst = (uint4*)(pbf + ((size_t)v*B + b)*C2 + cg*16);
    dst[0] = make_uint4(op[0], op[1], op[2], op[3]);
    dst[1] = make_uint4(op[4], op[5], op[6], op[7]);
}

// ---------------- conv3 MFMA: h3[b][o3][v], M=NP*8, N=128, K=64 ----------------
__global__ __launch_bounds__(256) void k_conv3m(const ushort_t* __restrict__ pbf,
        const ushort_t* __restrict__ wsw3, const float* __restrict__ b3,
        float* __restrict__ h3) {
    int tid = threadIdx.x;
    int wave = tid >> 6, lane = tid & 63;
    int quad = lane >> 4, col = lane & 15;
    int m0 = blockIdx.x*64 + wave*16;
    int m = m0 + col;
    int mc = ((m >> 3) < NP) ? m : 0;
    f32x4 acc[8];
#pragma unroll
    for (int nt = 0; nt < 8; ++nt) acc[nt] = (f32x4){0.f, 0.f, 0.f, 0.f};
    float bv[8];
#pragma unroll
    for (int nt = 0; nt < 8; ++nt) bv[nt] = b3[nt*16 + col];
    const bf16x8* W = (const bf16x8*)wsw3;
#pragma unroll
    for (int ks = 0; ks < 2; ++ks) {
        bf16x8 a = *(const bf16x8*)(pbf + (size_t)mc*C2 + ks*32 + quad*8);
#pragma unroll
        for (int nt = 0; nt < 8; ++nt) {
            bf16x8 bf = W[(ks*8 + nt)*64 + lane];
            acc[nt] = __builtin_amdgcn_mfma_f32_16x16x32_bf16(a, bf, acc[nt], 0, 0, 0);
        }
    }
#pragma unroll
    for (int r = 0; r < 4; ++r) {
        int mm = m0 + quad*4 + r;
        int v = mm >> 3, b = mm & 7;
        if (v < NP) {
#pragma unroll
            for (int nt = 0; nt < 8; ++nt) {
                int o3 = nt*16 + col;
                h3[(size_t)b*FCK + (size_t)o3*NP + v] = fmaxf(acc[nt][r] + bv[nt], 0.f);
            }
        }
    }
}

// ---------------- fc: split-K partials over chunks of 128 (float4 staging) ----------------
__global__ __launch_bounds__(256) void k_fc(const float* __restrict__ h3,
        const float* __restrict__ Wfc, float* __restrict__ partial) {
    __shared__ float sH[B][128];
    __shared__ float sW[OC][129];
    int tid = threadIdx.x;
    int o = tid & 63;
    int tb = tid >> 6;
    float acc0 = 0.f, acc1 = 0.f;
    for (int ch = blockIdx.x; ch < NCHUNK; ch += FBLK) {
        size_t i0 = (size_t)ch * 128;
        __syncthreads();
        {
            int bb = tid >> 5, i4 = tid & 31;
            float4 f = *(const float4*)(h3 + (size_t)bb*FCK + i0 + i4*4);
            sH[bb][i4*4+0] = f.x; sH[bb][i4*4+1] = f.y;
            sH[bb][i4*4+2] = f.z; sH[bb][i4*4+3] = f.w;
        }
#pragma unroll
        for (int j = 0; j < 8; ++j) {
            int idx = tid + j*256;
            int oo = idx >> 5, i4 = idx & 31;
            float4 f = *(const float4*)(Wfc + (size_t)oo*FCK + i0 + i4*4);
            sW[oo][i4*4+0] = f.x; sW[oo][i4*4+1] = f.y;
            sW[oo][i4*4+2] = f.z; sW[oo][i4*4+3] = f.w;
        }
        __syncthreads();
#pragma unroll 8
        for (int ii = 0; ii < 128; ++ii) {
            float w = sW[o][ii];
            acc0 += w * sH[2*tb][ii];
            acc1 += w * sH[2*tb+1][ii];
        }
    }
    partial[((size_t)blockIdx.x*B + 2*tb  )*OC + o] = acc0;
    partial[((size_t)blockIdx.x*B + 2*tb+1)*OC + o] = acc1;
}

__global__ void k_fcred(const float* __restrict__ partial, const float* __restrict__ bfc,
        float* __restrict__ out) {
    int b = blockIdx.x;
    int o = threadIdx.x;
    float s = 0.f;
    for (int j = 0; j < FBLK; ++j) s += partial[((size_t)j*B + b)*OC + o];
    out[b*OC + o] = s + bfc[o];
}

extern "C" void kernel_launch(void* const* d_in, const int* in_sizes, int n_in,
                              void* d_out, int out_size, void* d_ws, size_t ws_size,
                              hipStream_t stream) {
    const float* x    = (const float*)d_in[0];
    const int*   nebs = (const int*)d_in[1];
    const float* W1   = (const float*)d_in[2];
    const float* b1   = (const float*)d_in[3];
    const float* W2   = (const float*)d_in[4];
    const float* b2   = (const float*)d_in[5];
    const float* W3   = (const float*)d_in[6];
    const float* b3   = (const float*)d_in[7];
    const float* Wfc  = (const float*)d_in[8];
    const float* bfc  = (const float*)d_in[9];
    float* out = (float*)d_out;

    char* ws = (char*)d_ws;
    ushort_t* h1bf = (ushort_t*)(ws);                  // 41,945,088 B
    ushort_t* h2bf = (ushort_t*)(ws + 42000000);       // 41,945,088 B
    ushort_t* pbf  = (ushort_t*)(ws + 84000000);       // 10,487,808 B
    float*    h3   = (float*)(ws + 96000000);          // 41,951,232 B
    ushort_t* wsw  = (ushort_t*)(ws + 140000000);      // 73,728 B
    float*    part = (float*)(ws + 141000000);         // 2,097,152 B
    ushort_t* wsw3 = wsw + 28672;

    k_wswz<<<144, 256, 0, stream>>>(W2, W3, wsw);
    k_conv1<<<1281, 256, 0, stream>>>(x, W1, b1, h1bf);
    k_conv2m<<<2561, 256, 0, stream>>>(h1bf, nebs, wsw, b2, h2bf);
    k_pool<<<1281, 256, 0, stream>>>(h2bf, nebs, pbf);
    k_conv3m<<<1281, 256, 0, stream>>>(pbf, wsw3, b3, h3);
    k_fc<<<FBLK, 256, 0, stream>>>(h3, Wfc, part);
    k_fcred<<<B, OC, 0, stream>>>(part, bfc, out);
}